// Round 1
// baseline (141.369 us; speedup 1.0000x reference)
//
#include <hip/hip_runtime.h>

typedef __attribute__((ext_vector_type(4))) float  f32x4;
typedef __attribute__((ext_vector_type(8))) __bf16 bf16x8;
typedef __attribute__((ext_vector_type(4))) __bf16 bf16x4;

#define LDA 72  // bf16 units; 144B row stride (16B aligned, bank-balanced for b128 reads)

__global__ __launch_bounds__(256, 2) void fused_nn(
    const float* __restrict__ x,
    const float* __restrict__ h_w1, const float* __restrict__ h_b1,
    const float* __restrict__ h_wh, const float* __restrict__ h_bh,
    const float* __restrict__ h_wo, const float* __restrict__ h_bo,
    const float* __restrict__ g_w1, const float* __restrict__ g_b1,
    const float* __restrict__ g_wh, const float* __restrict__ g_bh,
    const float* __restrict__ g_wo, const float* __restrict__ g_bo,
    float* __restrict__ out, int nTiles, int Btot)
{
  __shared__ __bf16 sA[256 * LDA];     // activation tile (256 rows x 64, padded)
  __shared__ __bf16 sW[3 * 4096];      // weights in B-fragment order, up to 3 layers
  __shared__ float  sLB[3][64];        // per-mfma-layer bias
  __shared__ float  sV1[64];           // h: h_w1[d,:]
  __shared__ float  sV2[64];           // h: h_b1[d,:]
  __shared__ float  sWo[64];           // output weights
  __shared__ float  sS[256];           // h: second[:,d] for this row tile
  __shared__ float  sOb;               // output bias scalar

  const int tid  = threadIdx.x;
  const int wid  = tid >> 6;
  const int lane = tid & 63;
  const int c    = lane & 15;
  const int g4   = lane >> 4;
  const int wr   = wid << 6;           // wave's row base within tile (64 rows/wave)

  const int bid  = blockIdx.x;
  const bool is_h = (bid < (nTiles << 6));
  int d = 0, tile;
  if (is_h) { d = bid / nTiles; tile = bid - d * nTiles; }
  else      { tile = bid - (nTiles << 6); }
  const int row0 = tile << 8;

  const int nMM = is_h ? 2 : 3;        // number of MFMA layers

  // ---- stage weights into B-fragment order (bf16) ----
  // frag f = nf*2+kk; lane l holds W[k][n], n = nf*16+(l&15), k = kk*32+(l>>4)*8+j
  for (int l = 0; l < nMM; ++l) {
    const float* gW = is_h ? (h_wh + (((l << 6) + d) << 12) / 64)  // (l*64+d)*4096
                           : (l == 0 ? g_w1 : g_wh + ((l - 1) << 12));
    if (is_h) gW = h_wh + ((l << 6) + d) * 4096;
    for (int i = tid; i < 4096; i += 256) {
      int k = i >> 6, n = i & 63;
      float w = gW[i];
      int idx = ((((n >> 4) << 1) | (k >> 5)) << 9)        // frag * 512
              + ((((k >> 3) & 3) << 4 | (n & 15)) << 3)    // lane * 8
              + (k & 7);                                   // + j
      sW[(l << 12) + idx] = (__bf16)w;
    }
  }

  if (is_h) {
    if (tid < 64) {
      sV1[tid]    = h_w1[(d << 6) + tid];
      sV2[tid]    = h_b1[(d << 6) + tid];
      sLB[0][tid] = h_bh[(d << 6) + tid];            // l=0: (0*64+d)*64
      sLB[1][tid] = h_bh[((64 + d) << 6) + tid];     // l=1: (64+d)*64
      sWo[tid]    = h_wo[(d << 6) + tid];
    }
    if (tid == 0) sOb = h_bo[d];
    sS[tid] = x[(row0 + tid) * 128 + 64 + d];        // second[:, d]
    __syncthreads();
    // h1 = relu(s * w1 + b1) -> sA (bf16), vectorized 8-wide writes
    #pragma unroll
    for (int i = 0; i < 8; ++i) {
      int row = (i << 5) + (tid >> 3);
      int c0  = (tid & 7) << 3;
      float s = sS[row];
      bf16x8 v;
      #pragma unroll
      for (int j = 0; j < 8; ++j)
        v[j] = (__bf16)fmaxf(fmaf(s, sV1[c0 + j], sV2[c0 + j]), 0.f);
      *(bf16x8*)&sA[row * LDA + c0] = v;
    }
  } else {
    if (tid < 64) {
      sLB[0][tid] = g_b1[tid];
      sLB[1][tid] = g_bh[tid];
      sLB[2][tid] = g_bh[64 + tid];
      sWo[tid]    = g_wo[tid];
    }
    if (tid == 0) sOb = g_bo[0];
    // first = x[:, :64] -> sA (bf16), coalesced float4 loads
    #pragma unroll
    for (int i = 0; i < 16; ++i) {
      int u = (i << 8) + tid;
      int row = u >> 4, c4 = (u & 15) << 2;
      const float4 v = *(const float4*)&x[(row0 + row) * 128 + c4];
      bf16x4 b;
      b[0] = (__bf16)v.x; b[1] = (__bf16)v.y; b[2] = (__bf16)v.z; b[3] = (__bf16)v.w;
      *(bf16x4*)&sA[row * LDA + c4] = b;
    }
  }
  __syncthreads();

  // ---- MFMA layer chain ----
  f32x4 acc[4][4];
  for (int l = 0; l < nMM; ++l) {
    // B-fragments for this layer (reused across all 4 m-frags)
    bf16x8 bw[4][2];
    #pragma unroll
    for (int nf = 0; nf < 4; ++nf)
      #pragma unroll
      for (int kk = 0; kk < 2; ++kk)
        bw[nf][kk] = *(const bf16x8*)&sW[(l << 12) + ((((nf << 1) | kk) << 6) + lane) * 8];

    // bias pre-loaded into C operand (added exactly once)
    #pragma unroll
    for (int nf = 0; nf < 4; ++nf) {
      float bv = sLB[l][(nf << 4) + c];
      f32x4 bvv = {bv, bv, bv, bv};
      #pragma unroll
      for (int m = 0; m < 4; ++m) acc[m][nf] = bvv;
    }

    #pragma unroll
    for (int kk = 0; kk < 2; ++kk) {
      bf16x8 a[4];
      #pragma unroll
      for (int m = 0; m < 4; ++m)
        a[m] = *(const bf16x8*)&sA[(wr + (m << 4) + c) * LDA + (kk << 5) + (g4 << 3)];
      #pragma unroll
      for (int m = 0; m < 4; ++m)
        #pragma unroll
        for (int nf = 0; nf < 4; ++nf)
          acc[m][nf] = __builtin_amdgcn_mfma_f32_16x16x32_bf16(a[m], bw[nf][kk], acc[m][nf], 0, 0, 0);
    }

    if (l < nMM - 1) {
      __syncthreads();   // everyone done reading sA
      // relu, downcast, write back to sA in A-operand layout
      // C/D layout: col = (nf<<4)+(lane&15), row = wr + (m<<4) + (lane>>4)*4 + r
      #pragma unroll
      for (int m = 0; m < 4; ++m)
        #pragma unroll
        for (int nf = 0; nf < 4; ++nf)
          #pragma unroll
          for (int r = 0; r < 4; ++r) {
            float v = fmaxf(acc[m][nf][r], 0.f);
            sA[(wr + (m << 4) + (g4 << 2) + r) * LDA + (nf << 4) + c] = (__bf16)v;
          }
      __syncthreads();
    }
  }

  // ---- fused output layer: relu -> dot with wo -> 16-lane reduce ----
  float rs[4][4];
  #pragma unroll
  for (int m = 0; m < 4; ++m)
    #pragma unroll
    for (int r = 0; r < 4; ++r) rs[m][r] = 0.f;

  #pragma unroll
  for (int nf = 0; nf < 4; ++nf) {
    float wv = sWo[(nf << 4) + c];
    #pragma unroll
    for (int m = 0; m < 4; ++m)
      #pragma unroll
      for (int r = 0; r < 4; ++r)
        rs[m][r] += fmaxf(acc[m][nf][r], 0.f) * wv;
  }
  // reduce across the 16-lane col group (xor masks 1,2,4,8 stay in-group)
  #pragma unroll
  for (int off = 1; off < 16; off <<= 1)
    #pragma unroll
    for (int m = 0; m < 4; ++m)
      #pragma unroll
      for (int r = 0; r < 4; ++r)
        rs[m][r] += __shfl_xor(rs[m][r], off);

  if (c == 0) {
    float ob = sOb;
    #pragma unroll
    for (int m = 0; m < 4; ++m)
      #pragma unroll
      for (int r = 0; r < 4; ++r) {
        int row = row0 + wr + (m << 4) + (g4 << 2) + r;
        if (is_h) out[(row << 6) + d] = rs[m][r] + ob;
        else      out[(Btot << 6) + row] = rs[m][r] + ob;
      }
  }
}

extern "C" void kernel_launch(void* const* d_in, const int* in_sizes, int n_in,
                              void* d_out, int out_size, void* d_ws, size_t ws_size,
                              hipStream_t stream) {
  const float* x    = (const float*)d_in[0];
  const float* h_w1 = (const float*)d_in[1];
  const float* h_b1 = (const float*)d_in[2];
  const float* h_wh = (const float*)d_in[3];
  const float* h_bh = (const float*)d_in[4];
  const float* h_wo = (const float*)d_in[5];
  const float* h_bo = (const float*)d_in[6];
  const float* g_w1 = (const float*)d_in[7];
  const float* g_b1 = (const float*)d_in[8];
  const float* g_wh = (const float*)d_in[9];
  const float* g_bh = (const float*)d_in[10];
  const float* g_wo = (const float*)d_in[11];
  const float* g_bo = (const float*)d_in[12];

  const int Btot   = in_sizes[0] / 128;   // 32768
  const int nTiles = Btot >> 8;           // 128 row tiles of 256
  dim3 grid(nTiles * 65), block(256);     // 64*nTiles h-blocks + nTiles g-blocks

  hipLaunchKernelGGL(fused_nn, grid, block, 0, stream,
                     x, h_w1, h_b1, h_wh, h_bh, h_wo, h_bo,
                     g_w1, g_b1, g_wh, g_bh, g_wo, g_bo,
                     (float*)d_out, nTiles, Btot);
}

// Round 2
// 67.150 us; speedup vs baseline: 2.1053x; 2.1053x over previous
//
#include <hip/hip_runtime.h>

typedef __attribute__((ext_vector_type(4))) float  f32x4;
typedef __attribute__((ext_vector_type(8))) __bf16 bf16x8;
typedef __attribute__((ext_vector_type(4))) __bf16 bf16x4;

#define LDA 72  // bf16 units; 144B row stride (16B aligned; b128 reads hit min-pass, b64 writes 2-way=free)

// ---------------- setup: reformat weights into A-fragment order (bf16) ----------------
// Swapped orientation: A-operand = W^T (m = output index, k = input index).
// A-frag for mfma_f32_16x16x32_bf16: lane (g4*16+c), elem j holds A[m=mf*16+c][k=kk*32+g4*8+j]
//   = W[k_in = kk*32+g4*8+j][m_out = mf*16+c].
// ws layout: frag f = mf*2+kk; elem index = matrix_base + f*512 + lane*8 + j  (coalesced store).
__global__ void reformat_w(const float* __restrict__ h_wh,
                           const float* __restrict__ g_w1,
                           const float* __restrict__ g_wh,
                           __bf16* __restrict__ wsH,   // [2*64][4096]
                           __bf16* __restrict__ wsG)   // [3][4096]
{
  int i = blockIdx.x * 256 + threadIdx.x;
  int j = i & 7, lane = (i >> 3) & 63, f = (i >> 9) & 7;
  int c = lane & 15, g4 = lane >> 4, mf = f >> 1, kk = f & 1;
  int krow = (kk << 5) + (g4 << 3) + j;   // input index
  int mcol = (mf << 4) + c;               // output index
  if (i < 524288) {                       // h: 2 layers * 64 heads * 4096
    int ld = i >> 12;                     // l*64 + d
    wsH[i] = (__bf16)h_wh[(ld << 12) + (krow << 6) + mcol];
  } else if (i < 524288 + 12288) {        // g: 3 matrices * 4096
    int t = i - 524288;
    int lg = t >> 12;
    const float* W = (lg == 0) ? g_w1 : g_wh + ((lg - 1) << 12);
    wsG[t] = (__bf16)W[(krow << 6) + mcol];
  }
}

// ---------------- main fused kernel ----------------
__global__ __launch_bounds__(256, 4) void fused_nn(
    const float* __restrict__ x,
    const float* __restrict__ h_w1, const float* __restrict__ h_b1,
    const float* __restrict__ h_bh,
    const float* __restrict__ h_wo, const float* __restrict__ h_bo,
    const float* __restrict__ g_b1,
    const float* __restrict__ g_bh,
    const float* __restrict__ g_wo, const float* __restrict__ g_bo,
    const __bf16* __restrict__ wsH, const __bf16* __restrict__ wsG,
    float* __restrict__ out, int nTiles, int Btot)
{
  __shared__ __align__(16) __bf16 sA[256 * LDA];  // activations [batch][h], 36864 B
  __shared__ __align__(16) float  sLB[3][64];     // per-layer bias
  __shared__ __align__(16) float  sWo[64];        // output weights
  __shared__ __align__(16) float  sV1[64];        // h: h_w1[d,:]
  __shared__ __align__(16) float  sV2[64];        // h: h_b1[d,:]
  __shared__ float  sS[256];                      // h: second[:,d]

  const int tid  = threadIdx.x;
  const int lane = tid & 63;
  const int wid  = tid >> 6;
  const int c    = lane & 15;
  const int g4   = lane >> 4;
  const int wn   = wid << 6;          // wave's 64 batch cols within tile

  const int bid  = blockIdx.x;
  const bool is_h = (bid < (nTiles << 6));
  int d = 0, tile;
  if (is_h) { d = bid / nTiles; tile = bid - d * nTiles; }
  else      { tile = bid - (nTiles << 6); }
  const int row0 = tile << 8;
  const int nMM  = is_h ? 2 : 3;

  if (is_h) {
    if (tid < 64) {
      sLB[0][tid] = h_bh[(d << 6) + tid];
      sLB[1][tid] = h_bh[((64 + d) << 6) + tid];
      sWo[tid]    = h_wo[(d << 6) + tid];
      sV1[tid]    = h_w1[(d << 6) + tid];
      sV2[tid]    = h_b1[(d << 6) + tid];
    }
    sS[tid] = x[(row0 + tid) * 128 + 64 + d];
    __syncthreads();
    // h1 = relu(s * w1 + b1) -> sA[batch][h]
    const int c0 = (tid & 7) << 3;
    const f32x4 w1a = *(const f32x4*)&sV1[c0];
    const f32x4 w1b = *(const f32x4*)&sV1[c0 + 4];
    const f32x4 b1a = *(const f32x4*)&sV2[c0];
    const f32x4 b1b = *(const f32x4*)&sV2[c0 + 4];
    #pragma unroll
    for (int i = 0; i < 8; ++i) {
      int row = (i << 5) + (tid >> 3);
      float s = sS[row];
      bf16x8 v;
      #pragma unroll
      for (int j = 0; j < 4; ++j) {
        v[j]     = (__bf16)fmaxf(fmaf(s, w1a[j], b1a[j]), 0.f);
        v[j + 4] = (__bf16)fmaxf(fmaf(s, w1b[j], b1b[j]), 0.f);
      }
      *(bf16x8*)&sA[row * LDA + c0] = v;
    }
  } else {
    if (tid < 64) {
      sLB[0][tid] = g_b1[tid];
      sLB[1][tid] = g_bh[tid];
      sLB[2][tid] = g_bh[64 + tid];
      sWo[tid]    = g_wo[tid];
    }
    // first = x[:, :64] -> sA (bf16)
    #pragma unroll
    for (int i = 0; i < 16; ++i) {
      int u = (i << 8) + tid;
      int row = u >> 4, c4 = (u & 15) << 2;
      const float4 v = *(const float4*)&x[(row0 + row) * 128 + c4];
      bf16x4 b;
      b[0] = (__bf16)v.x; b[1] = (__bf16)v.y; b[2] = (__bf16)v.z; b[3] = (__bf16)v.w;
      *(bf16x4*)&sA[row * LDA + c4] = b;
    }
  }
  __syncthreads();

  // ---- MFMA layer chain: D^T = W^T * H^T ----
  // C/D layout: col(n)=batch=lane&15 within n-frag; row(m)=h_out=(lane>>4)*4+r within m-frag.
  f32x4 acc[4][4];
  for (int l = 0; l < nMM; ++l) {
    const __bf16* wfrag = is_h ? (wsH + (((l << 6) + d) << 12)) : (wsG + (l << 12));

    #pragma unroll
    for (int mf = 0; mf < 4; ++mf) {
      f32x4 bv = *(const f32x4*)&sLB[l][(mf << 4) + (g4 << 2)];
      #pragma unroll
      for (int nf = 0; nf < 4; ++nf) acc[mf][nf] = bv;
    }

    #pragma unroll
    for (int kk = 0; kk < 2; ++kk) {
      bf16x8 aw[4], bh[4];
      #pragma unroll
      for (int mf = 0; mf < 4; ++mf)
        aw[mf] = *(const bf16x8*)&wfrag[((((mf << 1) | kk)) << 9) + (lane << 3)];
      #pragma unroll
      for (int nf = 0; nf < 4; ++nf)
        bh[nf] = *(const bf16x8*)&sA[(wn + (nf << 4) + c) * LDA + (kk << 5) + (g4 << 3)];
      #pragma unroll
      for (int mf = 0; mf < 4; ++mf)
        #pragma unroll
        for (int nf = 0; nf < 4; ++nf)
          acc[mf][nf] = __builtin_amdgcn_mfma_f32_16x16x32_bf16(aw[mf], bh[nf], acc[mf][nf], 0, 0, 0);
    }

    if (l < nMM - 1) {
      __syncthreads();   // all waves done reading sA
      // relu -> bf16x4 -> sA[batch][h_out]; 4 consecutive h_out per lane -> ds_write_b64
      #pragma unroll
      for (int mf = 0; mf < 4; ++mf)
        #pragma unroll
        for (int nf = 0; nf < 4; ++nf) {
          bf16x4 v;
          #pragma unroll
          for (int r = 0; r < 4; ++r) v[r] = (__bf16)fmaxf(acc[mf][nf][r], 0.f);
          *(bf16x4*)&sA[(wn + (nf << 4) + c) * LDA + (mf << 4) + (g4 << 2)] = v;
        }
      __syncthreads();
    }
  }

  // ---- fused output layer: relu -> dot(wo) over h, reduce across g4 groups ----
  float p[4] = {0.f, 0.f, 0.f, 0.f};
  #pragma unroll
  for (int mf = 0; mf < 4; ++mf) {
    f32x4 wv = *(const f32x4*)&sWo[(mf << 4) + (g4 << 2)];
    #pragma unroll
    for (int nf = 0; nf < 4; ++nf)
      #pragma unroll
      for (int r = 0; r < 4; ++r)
        p[nf] += fmaxf(acc[mf][nf][r], 0.f) * wv[r];
  }
  #pragma unroll
  for (int nf = 0; nf < 4; ++nf) {
    p[nf] += __shfl_xor(p[nf], 16);
    p[nf] += __shfl_xor(p[nf], 32);
  }
  // lane handles nf == its own g4 -> batch = wn + lane (static selects, no scratch)
  float sel = (g4 == 0) ? p[0] : (g4 == 1) ? p[1] : (g4 == 2) ? p[2] : p[3];
  int batch = row0 + wn + lane;
  float ob  = is_h ? h_bo[d] : g_bo[0];
  if (is_h) out[(batch << 6) + d]   = sel + ob;
  else      out[(Btot << 6) + batch] = sel + ob;
}

extern "C" void kernel_launch(void* const* d_in, const int* in_sizes, int n_in,
                              void* d_out, int out_size, void* d_ws, size_t ws_size,
                              hipStream_t stream) {
  const float* x    = (const float*)d_in[0];
  const float* h_w1 = (const float*)d_in[1];
  const float* h_b1 = (const float*)d_in[2];
  const float* h_wh = (const float*)d_in[3];
  const float* h_bh = (const float*)d_in[4];
  const float* h_wo = (const float*)d_in[5];
  const float* h_bo = (const float*)d_in[6];
  const float* g_w1 = (const float*)d_in[7];
  const float* g_b1 = (const float*)d_in[8];
  const float* g_wh = (const float*)d_in[9];
  const float* g_bh = (const float*)d_in[10];
  const float* g_wo = (const float*)d_in[11];
  const float* g_bo = (const float*)d_in[12];

  __bf16* wsH = (__bf16*)d_ws;                       // 2*64*4096 bf16 = 1 MB
  __bf16* wsG = (__bf16*)((char*)d_ws + 2 * 64 * 4096 * 2);  // 3*4096 bf16 = 24 KB

  const int Btot   = in_sizes[0] / 128;   // 32768
  const int nTiles = Btot >> 8;           // 128 row tiles of 256

  // setup: 524288 + 12288 = 536576 elements = 2096 * 256
  hipLaunchKernelGGL(reformat_w, dim3(2096), dim3(256), 0, stream,
                     h_wh, g_w1, g_wh, wsH, wsG);

  dim3 grid(nTiles * 65), block(256);
  hipLaunchKernelGGL(fused_nn, grid, block, 0, stream,
                     x, h_w1, h_b1, h_bh, h_wo, h_bo,
                     g_b1, g_bh, g_wo, g_bo,
                     (const __bf16*)wsH, (const __bf16*)wsG,
                     (float*)d_out, nTiles, Btot);
}